// Round 6
// baseline (233.378 us; speedup 1.0000x reference)
//
#include <hip/hip_runtime.h>
#include <hip/hip_bf16.h>
#include <stdint.h>

// CrissCrossAttention, MI355X gfx950.
// out = 2 * row-attention (column branch collapses exactly onto row branch).
// Pipeline: prep (cvt x->bf16 + transpose W->bf16) | fused QKV GEMM |
//           per-(b,h,r) MFMA attention | GEMM(+bias) -> fp32 out.
// r12: (1) cc_attn: V-transpose staging vectorized (8x bf16x2 writes, 2-way
//      bank = free, vs 16 scalar writes at 4-8-way) and softmax P routed
//      through a dedicated Ps buffer whose rows are wave-private ->
//      barriers 4 -> 2. Budget analysis shows non-QKV time rigidly ~168us
//      across r0-r11; cc_attn's scalar V-writes + barrier chain is the
//      computable culprit. (2) GEMMs reverted to r9 gemm256 (best: 59.4us;
//      r11's gemm128 2-blocks/CU kept waves/CU at 8 and regressed to 62.7).

typedef __bf16 bf16_t;
typedef __bf16 bf16x2 __attribute__((ext_vector_type(2)));
typedef __bf16 bf16x4v __attribute__((ext_vector_type(4)));
typedef __bf16 bf16x8 __attribute__((ext_vector_type(8)));
typedef float  f32x4  __attribute__((ext_vector_type(4)));

#define GLD16(gp, lp)                                                                  \
  __builtin_amdgcn_global_load_lds((__attribute__((address_space(1))) const void*)(gp),\
                                   (__attribute__((address_space(3))) void*)(lp),      \
                                   16, 0, 0)

__device__ __forceinline__ float  bf2f(bf16_t x) { return (float)x; }
__device__ __forceinline__ bf16_t f2bf(float x)  { return (bf16_t)x; }

// ---------------------------------------------------------------------------
// prep: fused (a) fp32->bf16 conversion of x (float4 loads) and
//              (b) weight transpose+cast WT[n][k] = (bf16)W[k][n].
// blocks [0, 16384): cvt; blocks [16384, 17408): wt (256 per matrix).
// ---------------------------------------------------------------------------
__global__ __launch_bounds__(256) void prep(
    const float* __restrict__ x,
    const float* __restrict__ Wq, const float* __restrict__ Wk,
    const float* __restrict__ Wv, const float* __restrict__ Wo,
    bf16_t* __restrict__ xbf, bf16_t* __restrict__ WT)
{
  __shared__ bf16_t tile[32][33];
  const int bid = blockIdx.x, tid = threadIdx.x;
  if (bid < 16384) {
    const int i = bid * 256 + tid;                 // 16384*256 = 4194304 exact
    float4 v = ((const float4*)x)[i];
    bf16x4v o;
    o[0] = f2bf(v.x); o[1] = f2bf(v.y); o[2] = f2bf(v.z); o[3] = f2bf(v.w);
    ((bf16x4v*)xbf)[i] = o;
  } else {
    const int k = bid - 16384;                     // 0..1023
    const int mat = k >> 8;                        // 0..3
    const float* W = (mat == 0) ? Wq : (mat == 1) ? Wk : (mat == 2) ? Wv : Wo;
    bf16_t* dst = WT + (size_t)mat * 262144;
    const int bx = k & 15, by = (k >> 4) & 15;
    const int tx = tid & 31, ty = tid >> 5;        // 32 x 8
    const int x0 = bx * 32, y0 = by * 32;
#pragma unroll
    for (int i = 0; i < 32; i += 8)
      tile[ty + i][tx] = f2bf(W[(size_t)(y0 + ty + i) * 512 + x0 + tx]);
    __syncthreads();
#pragma unroll
    for (int i = 0; i < 32; i += 8)
      dst[(size_t)(x0 + ty + i) * 512 + y0 + tx] = tile[tx][ty + i];
  }
}

// ---------------------------------------------------------------------------
// GEMM: C[M,Nd] = A[M,512] @ BT[Nd,512]^T (+bias), bf16 in, fp32 acc.
// 256x256 tile, 512 threads = 8 waves (2M x 4N), BK=64, K=512 -> 8 K-tiles.
// LDS 128KB: double-buffered A[256][64] + B[256][64], XOR-swizzled rows
//   (logical (row,seg16B) lives at byte row*128 + (seg*16 ^ ((row&7)<<4));
//    global_load_lds dest stays linear, source address pre-permuted - rule 21).
// K-tile = 8 phases x 8 MFMA (A-chunk c=0..3 x kk=0..1); phase p issues the
// ds_reads for phase p+1 (a[2] ping-pong; bk[2] per-kk sets read at pre/ph3).
// Tile boundary (between ph6 and ph7): vmcnt(0) [8 GLDs issued at ph0, ~6
// phases old -> free] + barrier + read next tile's bk0/a-c0k0 under ph7's
// MFMA. k0 frag set is dead by ph3 -> boundary overwrite is safe.
// XCD swizzle (proven r5): each XCD owns a contiguous m-band, n fastest.
// ---------------------------------------------------------------------------
template <bool STORE_F32>
__global__ __launch_bounds__(512, 2) void gemm256(
    const bf16_t* __restrict__ A,
    const bf16_t* __restrict__ BT,
    void* __restrict__ Cp,
    const float* __restrict__ bias,
    int Nd)
{
  __shared__ __align__(16) bf16_t smem[65536];   // 128 KB
  bf16_t* const sA = smem;            // [2][16384] = dbuf x 256 rows x 64
  bf16_t* const sB = smem + 32768;    // [2][16384]

  const int tid  = threadIdx.x;
  const int lane = tid & 63, w = tid >> 6;
  const int quad = lane >> 4, r16 = lane & 15;
  const int wr = w >> 2, wc = w & 3;             // wave grid 2 x 4
  const int wm = wr * 128, wn = wc * 64;

  // XCD-aware remap (8 XCDs, round-robin dispatch). gridDim.y = 128 m-tiles.
  const int G = gridDim.x;
  const int l = blockIdx.y * G + blockIdx.x;
  const int xcd = l & 7, slot = l >> 3;
  const int mb = xcd * (gridDim.y >> 3) + slot / G;
  const int nb = slot % G;
  const int m0 = mb * 256, n0 = nb * 256;

  // staging: call c stages rows [c*64, c*64+64); thread t -> row=t>>3,
  // 16B seg = (t&7) ^ (row&7)  (inverse of the read-side XOR swizzle).
  const int srow = tid >> 3;
  const int sseg = (tid & 7) ^ (srow & 7);
  const bf16_t* Ag = A  + (size_t)(m0 + srow) * 512 + sseg * 8;
  const bf16_t* Bg = BT + (size_t)(n0 + srow) * 512 + sseg * 8;
  const int sdst = w * 512;                      // per-wave 1KB chunk (elems)

  // prologue: tile 0 -> buf 0.
  GLD16(Bg,           sB + sdst);
  GLD16(Bg + 32768,   sB + 4096  + sdst);
  GLD16(Bg + 65536,   sB + 8192  + sdst);
  GLD16(Bg + 98304,   sB + 12288 + sdst);
  GLD16(Ag,           sA + sdst);
  GLD16(Ag + 32768,   sA + 4096  + sdst);
  GLD16(Ag + 65536,   sA + 8192  + sdst);
  GLD16(Ag + 98304,   sA + 12288 + sdst);

  f32x4 acc[8][4] = {};

  const int xsw   = (r16 & 7) << 4;              // read-side XOR swizzle
  const int koff0 = (quad * 16) ^ xsw;           // kk=0 within-row byte
  const int koff1 = (64 + quad * 16) ^ xsw;      // kk=1

  bf16x8 bk[2][4];                               // B frag sets per kk
  bf16x8 a[2][2];                                // A chunk ping-pong (2 i-frags)

#define RD_B(dst, base, kof)                                                     \
  _Pragma("unroll") for (int j_ = 0; j_ < 4; ++j_)                               \
    dst[j_] = *(const bf16x8*)((base) + (size_t)(wn + j_ * 16 + r16) * 128 + (kof));
#define RD_A2(dst, base, rowoff, kof)                                            \
  _Pragma("unroll") for (int i_ = 0; i_ < 2; ++i_)                               \
    dst[i_] = *(const bf16x8*)((base) + (size_t)(wm + (rowoff) + i_ * 16 + r16) * 128 + (kof));
#define MFMA8(r0, r1, av, bv)                                                    \
  __builtin_amdgcn_s_setprio(1);                                                 \
  _Pragma("unroll") for (int j_ = 0; j_ < 4; ++j_) {                             \
    acc[r0][j_] = __builtin_amdgcn_mfma_f32_16x16x32_bf16(av[0], bv[j_], acc[r0][j_], 0, 0, 0); \
    acc[r1][j_] = __builtin_amdgcn_mfma_f32_16x16x32_bf16(av[1], bv[j_], acc[r1][j_], 0, 0, 0); \
  }                                                                              \
  __builtin_amdgcn_s_setprio(0);

  asm volatile("s_waitcnt vmcnt(0)" ::: "memory");
  __builtin_amdgcn_s_barrier();

  // pre-read tile0 ph0 operands: B k0-set + A chunk0 k0 (buf 0)
  RD_B(bk[0], (const char*)sB, koff0);
  RD_A2(a[0], (const char*)sA, 0, koff0);

#pragma unroll
  for (int t = 0; t < 8; ++t) {
    const int p = t & 1, pn = p ^ 1;
    const char* sAp  = (const char*)(sA + p  * 16384);
    const char* sBp  = (const char*)(sB + p  * 16384);
    const char* sApn = (const char*)(sA + pn * 16384);
    const char* sBpn = (const char*)(sB + pn * 16384);

    // ph0: issue all 8 GLDs for tile t+1 (waited ~6.5 phases later)
    if (t < 7) {
      const int kn = (t + 1) * 64;
      bf16_t* const dA = sA + pn * 16384 + sdst;
      bf16_t* const dB = sB + pn * 16384 + sdst;
      GLD16(Bg + kn,          dB);
      GLD16(Bg + kn + 32768,  dB + 4096);
      GLD16(Bg + kn + 65536,  dB + 8192);
      GLD16(Bg + kn + 98304,  dB + 12288);
      GLD16(Ag + kn,          dA);
      GLD16(Ag + kn + 32768,  dA + 4096);
      GLD16(Ag + kn + 65536,  dA + 8192);
      GLD16(Ag + kn + 98304,  dA + 12288);
    }
    RD_A2(a[1], sAp, 32, koff0);                 // c1 k0
    MFMA8(0, 1, a[0], bk[0]);                    // ph0: c0 k0

    RD_A2(a[0], sAp, 64, koff0);                 // c2 k0
    MFMA8(2, 3, a[1], bk[0]);                    // ph1: c1 k0

    RD_A2(a[1], sAp, 96, koff0);                 // c3 k0
    MFMA8(4, 5, a[0], bk[0]);                    // ph2: c2 k0

    RD_B(bk[1], sBp, koff1);                     // B k1-set
    RD_A2(a[0], sAp, 0, koff1);                  // c0 k1
    MFMA8(6, 7, a[1], bk[0]);                    // ph3: c3 k0  (k0 set dies here)

    RD_A2(a[1], sAp, 32, koff1);                 // c1 k1
    MFMA8(0, 1, a[0], bk[1]);                    // ph4: c0 k1

    RD_A2(a[0], sAp, 64, koff1);                 // c2 k1
    MFMA8(2, 3, a[1], bk[1]);                    // ph5: c1 k1

    RD_A2(a[1], sAp, 96, koff1);                 // c3 k1
    MFMA8(4, 5, a[0], bk[1]);                    // ph6: c2 k1

    // tile boundary: fills for t+1 are ~6 phases old -> vmcnt(0) is free.
    // Boundary reads (next tile's bk0 + a-c0k0) ride under ph7's MFMA.
    if (t < 7) {
      asm volatile("s_waitcnt vmcnt(0)" ::: "memory");
      __builtin_amdgcn_s_barrier();
      RD_B(bk[0], sBpn, koff0);
      RD_A2(a[0], sApn, 0, koff0);
    }
    MFMA8(6, 7, a[1], bk[1]);                    // ph7: c3 k1
  }

  __syncthreads();                               // LDS reuse safety (epilogue)

  if (STORE_F32) {
    // fp32: quad-row gives 16 lanes x 4B = 64B contiguous -> direct stores.
    float* C = (float*)Cp;
#pragma unroll
    for (int i8 = 0; i8 < 8; ++i8) {
#pragma unroll
      for (int j = 0; j < 4; ++j) {
        const int row = m0 + wm + i8 * 16 + quad * 4;
        const int col = n0 + wn + j * 16 + r16;
        const float bv = bias ? bias[col] : 0.0f;
#pragma unroll
        for (int rg = 0; rg < 4; ++rg)
          C[(size_t)(row + rg) * Nd + col] = acc[i8][j][rg] + bv;
      }
    }
  } else {
    // bf16: LDS transpose (pitch 264 elems = 528B, 16B-aligned, rows-of-4
    // land 16 banks apart -> ~2-way) then 16B/lane 512B-contiguous stores.
    bf16_t* Es = smem;                           // 128 x 264 = 33792 elems
    bf16_t* C  = (bf16_t*)Cp;
#pragma unroll
    for (int pr = 0; pr < 2; ++pr) {             // m-half rounds
      if (pr) __syncthreads();
      if (wr == pr) {
#pragma unroll
        for (int i8 = 0; i8 < 8; ++i8)
#pragma unroll
          for (int j = 0; j < 4; ++j)
#pragma unroll
            for (int rg = 0; rg < 4; ++rg)
              Es[(size_t)(i8 * 16 + quad * 4 + rg) * 264 + wn + j * 16 + r16] =
                  f2bf(acc[i8][j][rg]);
      }
      __syncthreads();
#pragma unroll
      for (int ps = 0; ps < 8; ++ps) {
        const int row = ps * 16 + (tid >> 5);
        const int cs  = (tid & 31) * 8;
        *(bf16x8*)&C[(size_t)(m0 + pr * 128 + row) * Nd + n0 + cs] =
            *(const bf16x8*)&Es[(size_t)row * 264 + cs];
      }
    }
  }
#undef RD_B
#undef RD_A2
#undef MFMA8
}

// ---------------------------------------------------------------------------
// Criss-cross attention: one WG per (b, h, r) group; 64x64 scores.
// QKV interleaved [32768][1536] (Q|K|V sections of 512 cols each).
// S = Q K^T * 0.125 (MFMA) -> in-register softmax (x2 folded) -> O = P @ V.
// r12 structure:
//  - V staged transposed with VECTORIZED bf16x2 writes (2 rows per thread):
//    bank pattern (24*s8 + j) % 32 = exact 2-way = free. Replaces 16 scalar
//    writes at 4-8-way conflicts (the dominant LDS cost of the old kernel).
//  - P goes to a dedicated Ps buffer. Qs/Ps rows are WAVE-PRIVATE (wave w
//    only touches rows [16w,16w+16)), so no barriers around softmax/PV.
//    Barriers: 4 -> 2 (after stage; before epilogue store-read).
//  - LDS 36.6 KB -> 4 blocks/CU co-resident.
// ---------------------------------------------------------------------------
__global__ __launch_bounds__(256) void cc_attn(
    const bf16_t* __restrict__ QKV, bf16_t* __restrict__ Aout)
{
  __shared__ __align__(16) bf16_t Qs[64 * 72];   // Q rows (wave-private); later O epilogue
  __shared__ __align__(16) bf16_t Ks[64 * 72];   // K rows (all waves read)
  __shared__ __align__(16) bf16_t VsT[64 * 70];  // V^T [dd][k] (all waves read)
  __shared__ __align__(16) bf16_t Ps[64 * 72];   // P rows (wave-private)

  const int gidx = blockIdx.x;                   // 8*8*64 = 4096 groups
  const int r = gidx & 63, h = (gidx >> 6) & 7, b = gidx >> 9;
  const int tid = threadIdx.x, lane = tid & 63, w = tid >> 6;
  const int quad = lane >> 4, r16 = lane & 15;
  const size_t row0 = (size_t)b * 4096 + (size_t)r * 64;   // first token row of group

  // ---- stage Q/K: thread t -> (row=t>>2, 16-elem seg=t&3)
  {
    const int row = tid >> 2, seg = tid & 3;
    const bf16_t* gp = QKV + (row0 + row) * 1536 + h * 64 + seg * 16;
    *(bf16x8*)&Qs[row * 72 + seg * 16]     = *(const bf16x8*)&gp[0];
    *(bf16x8*)&Qs[row * 72 + seg * 16 + 8] = *(const bf16x8*)&gp[8];
    *(bf16x8*)&Ks[row * 72 + seg * 16]     = *(const bf16x8*)&gp[512];
    *(bf16x8*)&Ks[row * 72 + seg * 16 + 8] = *(const bf16x8*)&gp[520];
  }
  // ---- stage V transposed, vectorized: thread t -> rows (r2, r2+1), dd-oct s8
  {
    const int r2 = (tid >> 3) * 2, s8 = tid & 7;
    const bf16_t* gv = QKV + (row0 + r2) * 1536 + h * 64 + 1024 + s8 * 8;
    bf16x8 vA = *(const bf16x8*)&gv[0];
    bf16x8 vB = *(const bf16x8*)&gv[1536];       // row r2+1
#pragma unroll
    for (int e = 0; e < 8; ++e) {
      bf16x2 pr; pr[0] = vA[e]; pr[1] = vB[e];
      *(bf16x2*)&VsT[(s8 * 8 + e) * 70 + r2] = pr;   // VsT[dd][k], k pair
    }
  }
  __syncthreads();

  // ---- S = (Q K^T); wave w owns score rows [16w, 16w+16)
  f32x4 sacc[4] = {};
#pragma unroll
  for (int ks = 0; ks < 2; ++ks) {
    bf16x8 aq = *(const bf16x8*)&Qs[(w * 16 + r16) * 72 + ks * 32 + quad * 8];
#pragma unroll
    for (int nj = 0; nj < 4; ++nj) {
      bf16x8 bkf = *(const bf16x8*)&Ks[(nj * 16 + r16) * 72 + ks * 32 + quad * 8];
      sacc[nj] = __builtin_amdgcn_mfma_f32_16x16x32_bf16(aq, bkf, sacc[nj], 0, 0, 0);
    }
  }

  // ---- in-register softmax. Lane holds S[row=w*16+quad*4+rg][col=nj*16+r16]*0.125.
  float ex[4][4];                      // [nj][rg]
  float sm[4];
#pragma unroll
  for (int rg = 0; rg < 4; ++rg) {
    float m = -3.0e38f;
#pragma unroll
    for (int nj = 0; nj < 4; ++nj) {
      ex[nj][rg] = sacc[nj][rg] * 0.125f;
      m = fmaxf(m, ex[nj][rg]);
    }
    m = fmaxf(m, __shfl_xor(m, 1));
    m = fmaxf(m, __shfl_xor(m, 2));
    m = fmaxf(m, __shfl_xor(m, 4));
    m = fmaxf(m, __shfl_xor(m, 8));
    float s = 0.f;
#pragma unroll
    for (int nj = 0; nj < 4; ++nj) { ex[nj][rg] = __expf(ex[nj][rg] - m); s += ex[nj][rg]; }
    s += __shfl_xor(s, 1);
    s += __shfl_xor(s, 2);
    s += __shfl_xor(s, 4);
    s += __shfl_xor(s, 8);
    sm[rg] = 2.0f / s;                 // x2: row+col branches identical
  }

  // ---- P -> Ps (wave-private rows; no barrier needed, lgkm ordering only)
#pragma unroll
  for (int nj = 0; nj < 4; ++nj)
#pragma unroll
    for (int rg = 0; rg < 4; ++rg)
      Ps[(w * 16 + quad * 4 + rg) * 72 + nj * 16 + r16] = f2bf(ex[nj][rg] * sm[rg]);

  // ---- O = P @ V via VsT (b128 b-frags)
  f32x4 oacc[4] = {};
#pragma unroll
  for (int ks = 0; ks < 2; ++ks) {
    bf16x8 ap = *(const bf16x8*)&Ps[(w * 16 + r16) * 72 + ks * 32 + quad * 8];
#pragma unroll
    for (int nj = 0; nj < 4; ++nj) {
      bf16x8 bv = *(const bf16x8*)&VsT[(nj * 16 + r16) * 70 + ks * 32 + quad * 8];
      oacc[nj] = __builtin_amdgcn_mfma_f32_16x16x32_bf16(ap, bv, oacc[nj], 0, 0, 0);
    }
  }

  // ---- epilogue through LDS (reuse Qs: rows are wave-private) -> 128B stores
  {
    bf16_t* Es = Qs;
#pragma unroll
    for (int nj = 0; nj < 4; ++nj)
#pragma unroll
      for (int rg = 0; rg < 4; ++rg)
        Es[(w * 16 + quad * 4 + rg) * 72 + nj * 16 + r16] = f2bf(oacc[nj][rg]);
    __syncthreads();
    const size_t obase = row0 * 512 + (size_t)h * 64;   // Aout [32768][512]
#pragma unroll
    for (int rd = 0; rd < 2; ++rd) {
      const int row = rd * 32 + (tid >> 3);
      const int col = (tid & 7) * 8;
      *(bf16x8*)&Aout[obase + (size_t)row * 512 + col] = *(const bf16x8*)&Es[row * 72 + col];
    }
  }
}

// ---------------------------------------------------------------------------
extern "C" void kernel_launch(void* const* d_in, const int* in_sizes, int n_in,
                              void* d_out, int out_size, void* d_ws, size_t ws_size,
                              hipStream_t stream)
{
  const float* x  = (const float*)d_in[0];
  const float* Wq = (const float*)d_in[1];
  const float* Wk = (const float*)d_in[2];
  const float* Wv = (const float*)d_in[3];
  const float* Wo = (const float*)d_in[4];
  const float* bo = (const float*)d_in[5];

  bf16_t* ws = (bf16_t*)d_ws;
  // workspace (bf16 elems):
  //   WT  : 4 x 262144   @ 0           (Wq|Wk|Wv rows 0..1535 stacked, then Wo)
  //   xbf : 16,777,216   @ 1,048,576   (dead after QKV GEMM; Ab aliases it)
  //   QKV : 50,331,648   @ 17,825,792  ([32768][1536] interleaved Q|K|V)
  // total 68,157,440 elems = 136,314,880 bytes
  bf16_t* WT  = ws;
  bf16_t* xbf = ws + 1048576;
  bf16_t* QKV = xbf + 16777216;
  bf16_t* Ab  = xbf;

  prep<<<dim3(17408), 256, 0, stream>>>(x, Wq, Wk, Wv, Wo, xbf, WT);

  // fused QKV projection: B = stacked WTq|WTk|WTv (1536 rows), 256x256 tiles
  gemm256<false><<<dim3(6, 128), 512, 0, stream>>>(xbf, WT, QKV, nullptr, 1536);

  cc_attn<<<dim3(4096), 256, 0, stream>>>(QKV, Ab);

  gemm256<true><<<dim3(2, 128), 512, 0, stream>>>(Ab, WT + 786432, d_out, bo, 512);
}

// Round 7
// 231.539 us; speedup vs baseline: 1.0079x; 1.0079x over previous
//
#include <hip/hip_runtime.h>
#include <hip/hip_bf16.h>
#include <stdint.h>

// CrissCrossAttention, MI355X gfx950.
// out = 2 * row-attention (column branch collapses exactly onto row branch).
// Pipeline: prep (cvt x->bf16 + transpose W->bf16) | QKV projection as 3
//           per-section GEMM launches | per-(b,h,r) MFMA attention |
//           GEMM(+bias) -> fp32 out.
// r13: VISIBILITY round. QKV GEMM split into 3 launches (Q|K|V sections,
//      grid (2,128)=256 blocks=1/CU each, ~21us). The harness top-5 floods
//      with the slowest kernel class; dropping the QKV dispatch below the
//      other kernels exposes the true time budget (attn / out-proj / prep)
//      which has been invisible across r0-r12 (~100us of the 230us total is
//      unattributed). A re-reads are L3-served (FETCH counts HBM only);
//      expected cost ~4us of launch gaps. Everything else identical to r12.

typedef __bf16 bf16_t;
typedef __bf16 bf16x2 __attribute__((ext_vector_type(2)));
typedef __bf16 bf16x4v __attribute__((ext_vector_type(4)));
typedef __bf16 bf16x8 __attribute__((ext_vector_type(8)));
typedef float  f32x4  __attribute__((ext_vector_type(4)));

#define GLD16(gp, lp)                                                                  \
  __builtin_amdgcn_global_load_lds((__attribute__((address_space(1))) const void*)(gp),\
                                   (__attribute__((address_space(3))) void*)(lp),      \
                                   16, 0, 0)

__device__ __forceinline__ float  bf2f(bf16_t x) { return (float)x; }
__device__ __forceinline__ bf16_t f2bf(float x)  { return (bf16_t)x; }

// ---------------------------------------------------------------------------
// prep: fused (a) fp32->bf16 conversion of x (float4 loads) and
//              (b) weight transpose+cast WT[n][k] = (bf16)W[k][n].
// blocks [0, 16384): cvt; blocks [16384, 17408): wt (256 per matrix).
// ---------------------------------------------------------------------------
__global__ __launch_bounds__(256) void prep(
    const float* __restrict__ x,
    const float* __restrict__ Wq, const float* __restrict__ Wk,
    const float* __restrict__ Wv, const float* __restrict__ Wo,
    bf16_t* __restrict__ xbf, bf16_t* __restrict__ WT)
{
  __shared__ bf16_t tile[32][33];
  const int bid = blockIdx.x, tid = threadIdx.x;
  if (bid < 16384) {
    const int i = bid * 256 + tid;                 // 16384*256 = 4194304 exact
    float4 v = ((const float4*)x)[i];
    bf16x4v o;
    o[0] = f2bf(v.x); o[1] = f2bf(v.y); o[2] = f2bf(v.z); o[3] = f2bf(v.w);
    ((bf16x4v*)xbf)[i] = o;
  } else {
    const int k = bid - 16384;                     // 0..1023
    const int mat = k >> 8;                        // 0..3
    const float* W = (mat == 0) ? Wq : (mat == 1) ? Wk : (mat == 2) ? Wv : Wo;
    bf16_t* dst = WT + (size_t)mat * 262144;
    const int bx = k & 15, by = (k >> 4) & 15;
    const int tx = tid & 31, ty = tid >> 5;        // 32 x 8
    const int x0 = bx * 32, y0 = by * 32;
#pragma unroll
    for (int i = 0; i < 32; i += 8)
      tile[ty + i][tx] = f2bf(W[(size_t)(y0 + ty + i) * 512 + x0 + tx]);
    __syncthreads();
#pragma unroll
    for (int i = 0; i < 32; i += 8)
      dst[(size_t)(x0 + ty + i) * 512 + y0 + tx] = tile[tx][ty + i];
  }
}

// ---------------------------------------------------------------------------
// GEMM: C[M,Nd] = A[M,512] @ BT[Nb,512]^T (+bias), bf16 in, fp32 acc.
// 256x256 tile, 512 threads = 8 waves (2M x 4N), BK=64, K=512 -> 8 K-tiles.
// LDS 128KB: double-buffered A[256][64] + B[256][64], XOR-swizzled rows
//   (logical (row,seg16B) lives at byte row*128 + (seg*16 ^ ((row&7)<<4));
//    global_load_lds dest stays linear, source address pre-permuted - rule 21).
// K-tile = 8 phases x 8 MFMA (A-chunk c=0..3 x kk=0..1); phase p issues the
// ds_reads for phase p+1. Tile boundary: aged vmcnt(0) + barrier; boundary
// reads ride under ph7's MFMA. XCD swizzle: m-band per XCD, n fastest.
// Nb = BT row count (n extent of this launch); Nd = C row pitch.
// ---------------------------------------------------------------------------
template <bool STORE_F32>
__global__ __launch_bounds__(512, 2) void gemm256(
    const bf16_t* __restrict__ A,
    const bf16_t* __restrict__ BT,
    void* __restrict__ Cp,
    const float* __restrict__ bias,
    int Nd)
{
  __shared__ __align__(16) bf16_t smem[65536];   // 128 KB
  bf16_t* const sA = smem;            // [2][16384] = dbuf x 256 rows x 64
  bf16_t* const sB = smem + 32768;    // [2][16384]

  const int tid  = threadIdx.x;
  const int lane = tid & 63, w = tid >> 6;
  const int quad = lane >> 4, r16 = lane & 15;
  const int wr = w >> 2, wc = w & 3;             // wave grid 2 x 4
  const int wm = wr * 128, wn = wc * 64;

  // XCD-aware remap (8 XCDs, round-robin dispatch). gridDim.y = 128 m-tiles.
  const int G = gridDim.x;
  const int l = blockIdx.y * G + blockIdx.x;
  const int xcd = l & 7, slot = l >> 3;
  const int mb = xcd * (gridDim.y >> 3) + slot / G;
  const int nb = slot % G;
  const int m0 = mb * 256, n0 = nb * 256;

  // staging: call c stages rows [c*64, c*64+64); thread t -> row=t>>3,
  // 16B seg = (t&7) ^ (row&7)  (inverse of the read-side XOR swizzle).
  const int srow = tid >> 3;
  const int sseg = (tid & 7) ^ (srow & 7);
  const bf16_t* Ag = A  + (size_t)(m0 + srow) * 512 + sseg * 8;
  const bf16_t* Bg = BT + (size_t)(n0 + srow) * 512 + sseg * 8;
  const int sdst = w * 512;                      // per-wave 1KB chunk (elems)

  // prologue: tile 0 -> buf 0.
  GLD16(Bg,           sB + sdst);
  GLD16(Bg + 32768,   sB + 4096  + sdst);
  GLD16(Bg + 65536,   sB + 8192  + sdst);
  GLD16(Bg + 98304,   sB + 12288 + sdst);
  GLD16(Ag,           sA + sdst);
  GLD16(Ag + 32768,   sA + 4096  + sdst);
  GLD16(Ag + 65536,   sA + 8192  + sdst);
  GLD16(Ag + 98304,   sA + 12288 + sdst);

  f32x4 acc[8][4] = {};

  const int xsw   = (r16 & 7) << 4;              // read-side XOR swizzle
  const int koff0 = (quad * 16) ^ xsw;           // kk=0 within-row byte
  const int koff1 = (64 + quad * 16) ^ xsw;      // kk=1

  bf16x8 bk[2][4];                               // B frag sets per kk
  bf16x8 a[2][2];                                // A chunk ping-pong (2 i-frags)

#define RD_B(dst, base, kof)                                                     \
  _Pragma("unroll") for (int j_ = 0; j_ < 4; ++j_)                               \
    dst[j_] = *(const bf16x8*)((base) + (size_t)(wn + j_ * 16 + r16) * 128 + (kof));
#define RD_A2(dst, base, rowoff, kof)                                            \
  _Pragma("unroll") for (int i_ = 0; i_ < 2; ++i_)                               \
    dst[i_] = *(const bf16x8*)((base) + (size_t)(wm + (rowoff) + i_ * 16 + r16) * 128 + (kof));
#define MFMA8(r0, r1, av, bv)                                                    \
  __builtin_amdgcn_s_setprio(1);                                                 \
  _Pragma("unroll") for (int j_ = 0; j_ < 4; ++j_) {                             \
    acc[r0][j_] = __builtin_amdgcn_mfma_f32_16x16x32_bf16(av[0], bv[j_], acc[r0][j_], 0, 0, 0); \
    acc[r1][j_] = __builtin_amdgcn_mfma_f32_16x16x32_bf16(av[1], bv[j_], acc[r1][j_], 0, 0, 0); \
  }                                                                              \
  __builtin_amdgcn_s_setprio(0);

  asm volatile("s_waitcnt vmcnt(0)" ::: "memory");
  __builtin_amdgcn_s_barrier();

  // pre-read tile0 ph0 operands: B k0-set + A chunk0 k0 (buf 0)
  RD_B(bk[0], (const char*)sB, koff0);
  RD_A2(a[0], (const char*)sA, 0, koff0);

#pragma unroll
  for (int t = 0; t < 8; ++t) {
    const int p = t & 1, pn = p ^ 1;
    const char* sAp  = (const char*)(sA + p  * 16384);
    const char* sBp  = (const char*)(sB + p  * 16384);
    const char* sApn = (const char*)(sA + pn * 16384);
    const char* sBpn = (const char*)(sB + pn * 16384);

    // ph0: issue all 8 GLDs for tile t+1 (waited ~6.5 phases later)
    if (t < 7) {
      const int kn = (t + 1) * 64;
      bf16_t* const dA = sA + pn * 16384 + sdst;
      bf16_t* const dB = sB + pn * 16384 + sdst;
      GLD16(Bg + kn,          dB);
      GLD16(Bg + kn + 32768,  dB + 4096);
      GLD16(Bg + kn + 65536,  dB + 8192);
      GLD16(Bg + kn + 98304,  dB + 12288);
      GLD16(Ag + kn,          dA);
      GLD16(Ag + kn + 32768,  dA + 4096);
      GLD16(Ag + kn + 65536,  dA + 8192);
      GLD16(Ag + kn + 98304,  dA + 12288);
    }
    RD_A2(a[1], sAp, 32, koff0);                 // c1 k0
    MFMA8(0, 1, a[0], bk[0]);                    // ph0: c0 k0

    RD_A2(a[0], sAp, 64, koff0);                 // c2 k0
    MFMA8(2, 3, a[1], bk[0]);                    // ph1: c1 k0

    RD_A2(a[1], sAp, 96, koff0);                 // c3 k0
    MFMA8(4, 5, a[0], bk[0]);                    // ph2: c2 k0

    RD_B(bk[1], sBp, koff1);                     // B k1-set
    RD_A2(a[0], sAp, 0, koff1);                  // c0 k1
    MFMA8(6, 7, a[1], bk[0]);                    // ph3: c3 k0  (k0 set dies here)

    RD_A2(a[1], sAp, 32, koff1);                 // c1 k1
    MFMA8(0, 1, a[0], bk[1]);                    // ph4: c0 k1

    RD_A2(a[0], sAp, 64, koff1);                 // c2 k1
    MFMA8(2, 3, a[1], bk[1]);                    // ph5: c1 k1

    RD_A2(a[1], sAp, 96, koff1);                 // c3 k1
    MFMA8(4, 5, a[0], bk[1]);                    // ph6: c2 k1

    // tile boundary: fills for t+1 are ~6 phases old -> vmcnt(0) is free.
    // Boundary reads (next tile's bk0 + a-c0k0) ride under ph7's MFMA.
    if (t < 7) {
      asm volatile("s_waitcnt vmcnt(0)" ::: "memory");
      __builtin_amdgcn_s_barrier();
      RD_B(bk[0], sBpn, koff0);
      RD_A2(a[0], sApn, 0, koff0);
    }
    MFMA8(6, 7, a[1], bk[1]);                    // ph7: c3 k1
  }

  __syncthreads();                               // LDS reuse safety (epilogue)

  if (STORE_F32) {
    // fp32: quad-row gives 16 lanes x 4B = 64B contiguous -> direct stores.
    float* C = (float*)Cp;
#pragma unroll
    for (int i8 = 0; i8 < 8; ++i8) {
#pragma unroll
      for (int j = 0; j < 4; ++j) {
        const int row = m0 + wm + i8 * 16 + quad * 4;
        const int col = n0 + wn + j * 16 + r16;
        const float bv = bias ? bias[col] : 0.0f;
#pragma unroll
        for (int rg = 0; rg < 4; ++rg)
          C[(size_t)(row + rg) * Nd + col] = acc[i8][j][rg] + bv;
      }
    }
  } else {
    // bf16: LDS transpose (pitch 264 elems = 528B, 16B-aligned, rows-of-4
    // land 16 banks apart -> ~2-way) then 16B/lane 512B-contiguous stores.
    bf16_t* Es = smem;                           // 128 x 264 = 33792 elems
    bf16_t* C  = (bf16_t*)Cp;
#pragma unroll
    for (int pr = 0; pr < 2; ++pr) {             // m-half rounds
      if (pr) __syncthreads();
      if (wr == pr) {
#pragma unroll
        for (int i8 = 0; i8 < 8; ++i8)
#pragma unroll
          for (int j = 0; j < 4; ++j)
#pragma unroll
            for (int rg = 0; rg < 4; ++rg)
              Es[(size_t)(i8 * 16 + quad * 4 + rg) * 264 + wn + j * 16 + r16] =
                  f2bf(acc[i8][j][rg]);
      }
      __syncthreads();
#pragma unroll
      for (int ps = 0; ps < 8; ++ps) {
        const int row = ps * 16 + (tid >> 5);
        const int cs  = (tid & 31) * 8;
        *(bf16x8*)&C[(size_t)(m0 + pr * 128 + row) * Nd + n0 + cs] =
            *(const bf16x8*)&Es[(size_t)row * 264 + cs];
      }
    }
  }
#undef RD_B
#undef RD_A2
#undef MFMA8
}

// ---------------------------------------------------------------------------
// Criss-cross attention: one WG per (b, h, r) group; 64x64 scores.
// QKV interleaved [32768][1536] (Q|K|V sections of 512 cols each).
// S = Q K^T * 0.125 (MFMA) -> in-register softmax (x2 folded) -> O = P @ V.
// V staged transposed with vectorized bf16x2 writes (2-way bank = free);
// P in dedicated wave-private Ps buffer -> 2 barriers total.
// ---------------------------------------------------------------------------
__global__ __launch_bounds__(256) void cc_attn(
    const bf16_t* __restrict__ QKV, bf16_t* __restrict__ Aout)
{
  __shared__ __align__(16) bf16_t Qs[64 * 72];   // Q rows (wave-private); later O epilogue
  __shared__ __align__(16) bf16_t Ks[64 * 72];   // K rows (all waves read)
  __shared__ __align__(16) bf16_t VsT[64 * 70];  // V^T [dd][k] (all waves read)
  __shared__ __align__(16) bf16_t Ps[64 * 72];   // P rows (wave-private)

  const int gidx = blockIdx.x;                   // 8*8*64 = 4096 groups
  const int r = gidx & 63, h = (gidx >> 6) & 7, b = gidx >> 9;
  const int tid = threadIdx.x, lane = tid & 63, w = tid >> 6;
  const int quad = lane >> 4, r16 = lane & 15;
  const size_t row0 = (size_t)b * 4096 + (size_t)r * 64;   // first token row of group

  // ---- stage Q/K: thread t -> (row=t>>2, 16-elem seg=t&3)
  {
    const int row = tid >> 2, seg = tid & 3;
    const bf16_t* gp = QKV + (row0 + row) * 1536 + h * 64 + seg * 16;
    *(bf16x8*)&Qs[row * 72 + seg * 16]     = *(const bf16x8*)&gp[0];
    *(bf16x8*)&Qs[row * 72 + seg * 16 + 8] = *(const bf16x8*)&gp[8];
    *(bf16x8*)&Ks[row * 72 + seg * 16]     = *(const bf16x8*)&gp[512];
    *(bf16x8*)&Ks[row * 72 + seg * 16 + 8] = *(const bf16x8*)&gp[520];
  }
  // ---- stage V transposed, vectorized: thread t -> rows (r2, r2+1), dd-oct s8
  {
    const int r2 = (tid >> 3) * 2, s8 = tid & 7;
    const bf16_t* gv = QKV + (row0 + r2) * 1536 + h * 64 + 1024 + s8 * 8;
    bf16x8 vA = *(const bf16x8*)&gv[0];
    bf16x8 vB = *(const bf16x8*)&gv[1536];       // row r2+1
#pragma unroll
    for (int e = 0; e < 8; ++e) {
      bf16x2 pr; pr[0] = vA[e]; pr[1] = vB[e];
      *(bf16x2*)&VsT[(s8 * 8 + e) * 70 + r2] = pr;   // VsT[dd][k], k pair
    }
  }
  __syncthreads();

  // ---- S = (Q K^T); wave w owns score rows [16w, 16w+16)
  f32x4 sacc[4] = {};
#pragma unroll
  for (int ks = 0; ks < 2; ++ks) {
    bf16x8 aq = *(const bf16x8*)&Qs[(w * 16 + r16) * 72 + ks * 32 + quad * 8];
#pragma unroll
    for (int nj = 0; nj < 4; ++nj) {
      bf16x8 bkf = *(const bf16x8*)&Ks[(nj * 16 + r16) * 72 + ks * 32 + quad * 8];
      sacc[nj] = __builtin_amdgcn_mfma_f32_16x16x32_bf16(aq, bkf, sacc[nj], 0, 0, 0);
    }
  }

  // ---- in-register softmax. Lane holds S[row=w*16+quad*4+rg][col=nj*16+r16]*0.125.
  float ex[4][4];                      // [nj][rg]
  float sm[4];
#pragma unroll
  for (int rg = 0; rg < 4; ++rg) {
    float m = -3.0e38f;
#pragma unroll
    for (int nj = 0; nj < 4; ++nj) {
      ex[nj][rg] = sacc[nj][rg] * 0.125f;
      m = fmaxf(m, ex[nj][rg]);
    }
    m = fmaxf(m, __shfl_xor(m, 1));
    m = fmaxf(m, __shfl_xor(m, 2));
    m = fmaxf(m, __shfl_xor(m, 4));
    m = fmaxf(m, __shfl_xor(m, 8));
    float s = 0.f;
#pragma unroll
    for (int nj = 0; nj < 4; ++nj) { ex[nj][rg] = __expf(ex[nj][rg] - m); s += ex[nj][rg]; }
    s += __shfl_xor(s, 1);
    s += __shfl_xor(s, 2);
    s += __shfl_xor(s, 4);
    s += __shfl_xor(s, 8);
    sm[rg] = 2.0f / s;                 // x2: row+col branches identical
  }

  // ---- P -> Ps (wave-private rows; no barrier needed, lgkm ordering only)
#pragma unroll
  for (int nj = 0; nj < 4; ++nj)
#pragma unroll
    for (int rg = 0; rg < 4; ++rg)
      Ps[(w * 16 + quad * 4 + rg) * 72 + nj * 16 + r16] = f2bf(ex[nj][rg] * sm[rg]);

  // ---- O = P @ V via VsT (b128 b-frags)
  f32x4 oacc[4] = {};
#pragma unroll
  for (int ks = 0; ks < 2; ++ks) {
    bf16x8 ap = *(const bf16x8*)&Ps[(w * 16 + r16) * 72 + ks * 32 + quad * 8];
#pragma unroll
    for (int nj = 0; nj < 4; ++nj) {
      bf16x8 bv = *(const bf16x8*)&VsT[(nj * 16 + r16) * 70 + ks * 32 + quad * 8];
      oacc[nj] = __builtin_amdgcn_mfma_f32_16x16x32_bf16(ap, bv, oacc[nj], 0, 0, 0);
    }
  }

  // ---- epilogue through LDS (reuse Qs: rows are wave-private) -> 128B stores
  {
    bf16_t* Es = Qs;
#pragma unroll
    for (int nj = 0; nj < 4; ++nj)
#pragma unroll
      for (int rg = 0; rg < 4; ++rg)
        Es[(w * 16 + quad * 4 + rg) * 72 + nj * 16 + r16] = f2bf(oacc[nj][rg]);
    __syncthreads();
    const size_t obase = row0 * 512 + (size_t)h * 64;   // Aout [32768][512]
#pragma unroll
    for (int rd = 0; rd < 2; ++rd) {
      const int row = rd * 32 + (tid >> 3);
      const int col = (tid & 7) * 8;
      *(bf16x8*)&Aout[obase + (size_t)row * 512 + col] = *(const bf16x8*)&Es[row * 72 + col];
    }
  }
}

// ---------------------------------------------------------------------------
extern "C" void kernel_launch(void* const* d_in, const int* in_sizes, int n_in,
                              void* d_out, int out_size, void* d_ws, size_t ws_size,
                              hipStream_t stream)
{
  const float* x  = (const float*)d_in[0];
  const float* Wq = (const float*)d_in[1];
  const float* Wk = (const float*)d_in[2];
  const float* Wv = (const float*)d_in[3];
  const float* Wo = (const float*)d_in[4];
  const float* bo = (const float*)d_in[5];

  bf16_t* ws = (bf16_t*)d_ws;
  // workspace (bf16 elems):
  //   WT  : 4 x 262144   @ 0           (Wq|Wk|Wv rows 0..1535 stacked, then Wo)
  //   xbf : 16,777,216   @ 1,048,576   (dead after QKV GEMM; Ab aliases it)
  //   QKV : 50,331,648   @ 17,825,792  ([32768][1536] interleaved Q|K|V)
  // total 68,157,440 elems = 136,314,880 bytes
  bf16_t* WT  = ws;
  bf16_t* xbf = ws + 1048576;
  bf16_t* QKV = xbf + 16777216;
  bf16_t* Ab  = xbf;

  prep<<<dim3(17408), 256, 0, stream>>>(x, Wq, Wk, Wv, Wo, xbf, WT);

  // QKV projection: one launch per 512-col section (Q|K|V). 256 blocks each
  // = 1/CU, perfectly balanced; per-section B (0.5MB) L2-resident; A re-reads
  // served by L3. Drops the per-dispatch dur to ~21us so the profiler's top-5
  // exposes the真 budget of attn / out-proj / prep next round.
  for (int s = 0; s < 3; ++s)
    gemm256<false><<<dim3(2, 128), 512, 0, stream>>>(
        xbf, WT + (size_t)s * 262144, QKV + (size_t)s * 512, nullptr, 1536);

  cc_attn<<<dim3(4096), 256, 0, stream>>>(QKV, Ab);

  gemm256<true><<<dim3(2, 128), 512, 0, stream>>>(Ab, WT + 786432, d_out, bo, 512);
}